// Round 1
// baseline (465.958 us; speedup 1.0000x reference)
//
#include <hip/hip_runtime.h>
#include <stdint.h>
#include <stddef.h>

typedef __attribute__((ext_vector_type(8))) _Float16 f16x8;
typedef __attribute__((ext_vector_type(4))) float f32x4;
typedef __attribute__((ext_vector_type(2))) unsigned int u32x2;

#define D_IN 153
#define B_ROWS 262144
#define M_TILE 64
#define XB_STRIDE 168   // 336 B rows (mult of 16 B)
#define G1H_STRIDE 72   // 144 B rows (mult of 16 B; was 68)
#define H1_STRIDE 136   // 272 B rows
#define H2_STRIDE 72    // 144 B rows
#define G2S_STRIDE 40   // 80 B rows (mult of 16 B)

// swizzled f16 weight layout offsets (in u16 elements, all multiples of 512)
#define OFF_WP 0
#define SZ_WP (5*10*512)
#define OFF_WG1 (OFF_WP + SZ_WP)
#define SZ_WG1 (5*4*512)
#define OFF_WE1 (OFF_WG1 + SZ_WG1)
#define SZ_WE1 (8*5*8*512)
#define OFF_WE2 (OFF_WE1 + SZ_WE1)
#define SZ_WE2 (8*4*4*512)
#define OFF_WE3 (OFF_WE2 + SZ_WE2)
#define SZ_WE3 (8*2*512)
#define OFF_WG2 (OFF_WE3 + SZ_WE3)
#define SZ_WG2 (2*2*512)
#define OFF_WG3 (OFF_WG2 + SZ_WG2)
#define SZ_WG3 (1*512)
#define TOTAL_W (OFF_WG3 + SZ_WG3)   // 275968 u16 = 551936 B

__device__ __forceinline__ unsigned short f2h(float f) {
    _Float16 h = (_Float16)f;                 // v_cvt_f16_f32, RNE
    union { _Float16 h; unsigned short u; } v; v.h = h;
    return v.u;
}
__device__ __forceinline__ float h2f(unsigned short u) {
    union { unsigned short u; _Float16 h; } v; v.u = u;
    return (float)v.h;
}
__device__ __forceinline__ unsigned int pk2(float a, float b) {
    return (unsigned int)f2h(a) | ((unsigned int)f2h(b) << 16);
}

__device__ __forceinline__ f32x4 mfma16(f16x8 a, f16x8 b, f32x4 c) {
    return __builtin_amdgcn_mfma_f32_16x16x32_f16(a, b, c, 0, 0, 0);
}

// Activation fragment from LDS (works as A- OR B-operand: lane&15 -> row,
// quad -> k-octet). 16B contiguous per lane.
__device__ __forceinline__ f16x8 ldsA(const unsigned short* buf, int stride,
                                      int m0, int k0, int lane) {
    int row = m0 + (lane & 15);
    int col = k0 + (lane >> 4) * 8;
    return *(const f16x8*)(buf + row * stride + col);
}
// Weight fragment from pre-swizzled global: tile of 64 lanes x 16B
__device__ __forceinline__ f16x8 ldB(const unsigned short* ws, int tile, int lane) {
    return *(const f16x8*)(ws + (size_t)tile * 512 + lane * 8);
}

// relu(acc+bias) -> 4 packed f16 (4 consecutive cols) -> one ds_write_b64
__device__ __forceinline__ void stRelu4(unsigned short* dst, const f32x4 a, const f32x4 bv) {
    float v0 = fmaxf(a[0] + bv[0], 0.f);
    float v1 = fmaxf(a[1] + bv[1], 0.f);
    float v2 = fmaxf(a[2] + bv[2], 0.f);
    float v3 = fmaxf(a[3] + bv[3], 0.f);
    u32x2 w; w[0] = pk2(v0, v1); w[1] = pk2(v2, v3);
    *(u32x2*)dst = w;
}

// ---------------------------------------------------------------------------
// Weight conversion: fp32 -> fp16 in MFMA fragment-swizzled layout.
// (byte-identical to the passing version; layout serves both operand roles)
// ---------------------------------------------------------------------------
__global__ __launch_bounds__(256) void convert_weights(
        const float* __restrict__ Wp, const float* __restrict__ Wg1,
        const float* __restrict__ We1, const float* __restrict__ We2,
        const float* __restrict__ We3, const float* __restrict__ Wg2,
        const float* __restrict__ Wg3, unsigned short* __restrict__ ws) {
    int idx = blockIdx.x * 256 + threadIdx.x;
    if (idx >= TOTAL_W) return;
    int j = idx & 7;
    int lane = (idx >> 3) & 63;
    int t = idx >> 9;
    int quad = lane >> 4, nl = lane & 15;
    int kin = quad * 8 + j;
    float val = 0.f;
    if (idx < OFF_WG1) {                 // Wp [153][153], Kp=160 Np=160
        int kt = t / 10, nt = t % 10;
        int k = kt * 32 + kin, n = nt * 16 + nl;
        if (k < 153 && n < 153) val = Wp[k * 153 + n];
    } else if (idx < OFF_WE1) {          // Wg1 [153][64]
        int tt = t - (OFF_WG1 >> 9);
        int kt = tt / 4, nt = tt % 4;
        int k = kt * 32 + kin, n = nt * 16 + nl;
        if (k < 153) val = Wg1[k * 64 + n];
    } else if (idx < OFF_WE2) {          // We1 [8][153][128]
        int tt = t - (OFF_WE1 >> 9);
        int e = tt / 40, r = tt % 40, kt = r / 8, nt = r % 8;
        int k = kt * 32 + kin, n = nt * 16 + nl;
        if (k < 153) val = We1[((size_t)e * 153 + k) * 128 + n];
    } else if (idx < OFF_WE3) {          // We2 [8][128][64]
        int tt = t - (OFF_WE2 >> 9);
        int e = tt / 16, r = tt % 16, kt = r / 4, nt = r % 4;
        int k = kt * 32 + kin, n = nt * 16 + nl;
        val = We2[((size_t)e * 128 + k) * 64 + n];
    } else if (idx < OFF_WG2) {          // We3 [8][64][8], Np=16 (cols 8..15 zero)
        int tt = t - (OFF_WE3 >> 9);
        int e = tt / 2, kt = tt % 2;
        int k = kt * 32 + kin, n = nl;
        if (n < 8) val = We3[((size_t)e * 64 + k) * 8 + n];
    } else if (idx < OFF_WG3) {          // Wg2 [64][32]
        int tt = t - (OFF_WG2 >> 9);
        int kt = tt >> 1, nt = tt & 1;
        int k = kt * 32 + kin, n = nt * 16 + nl;
        val = Wg2[k * 32 + n];
    } else {                             // Wg3 [32][8] (cols 8..15 zero)
        int k = kin, n = nl;
        if (n < 8) val = Wg3[k * 8 + n];
    }
    ws[idx] = f2h(val);
}

// ---------------------------------------------------------------------------
// Fused MoE kernel. Changes vs 427µs version:
//  * All MFMAs operand-SWAPPED: mfma(W_frag, act_frag). Output C-layout now
//    has batch-row in lane&15 and 4 CONSECUTIVE output cols in the 4 regs ->
//    packed ds_write_b64 epilogues (4x fewer LDS writes), float4 bias loads,
//    b64 residual re-read, float4 global stores. Weight layout unchanged
//    (A/B fragment register layouts are identical).
//  * xp A-fragments (20 x f16x8 = 80 VGPR) hoisted into registers once,
//    reused by phase 3 + all 8 We1 phases (kills 160 ds_read_b128/wave).
//  * All LDS row strides multiples of 16 B.
// ---------------------------------------------------------------------------
__global__ __launch_bounds__(256, 3) void moe_main(
        const float* __restrict__ x,
        const float* __restrict__ ln_in_g, const float* __restrict__ ln_in_b,
        const float* __restrict__ bp,
        const float* __restrict__ bg1, const float* __restrict__ bg2,
        const float* __restrict__ bg3,
        const float* __restrict__ be1, const float* __restrict__ be2,
        const float* __restrict__ be3,
        const float* __restrict__ ln_out_g, const float* __restrict__ ln_out_b,
        const unsigned short* __restrict__ wsw,
        float* __restrict__ out) {
    const int tid = threadIdx.x;
    const int wave = tid >> 6, lane = tid & 63;
    const int quad = lane >> 4, nl = lane & 15;
    const size_t rowBase = (size_t)blockIdx.x * M_TILE;

    __shared__ __align__(16) char U[26624];  // xb -> g1h/g2s -> h1|h2
    __shared__ __align__(16) unsigned short xp[M_TILE * XB_STRIDE];  // x_proj f16
    __shared__ __align__(16) float gate[M_TILE * 8];
    unsigned short* xb  = (unsigned short*)U;              // [64][168] f16
    unsigned short* g1h = (unsigned short*)U;              // [64][72]  f16 (9216 B)
    unsigned short* g2s = (unsigned short*)(U + 17408);    // [64][40]  f16 (5120 B)
    unsigned short* h1  = (unsigned short*)U;              // [64][136] f16
    unsigned short* h2  = (unsigned short*)(U + 17408);    // [64][72]  f16

    const f32x4 fzero = {0.f, 0.f, 0.f, 0.f};

    // ---- Phase 1: input LayerNorm (4 threads per row) ----
    {
        int r = tid >> 2, seg = tid & 3;
        const float* xr = x + (rowBase + r) * (size_t)D_IN;
        float vals[39];
        float s = 0.f, sq = 0.f;
        #pragma unroll
        for (int i = 0; i < 39; i++) {
            int c = seg + i * 4;
            float v = (c < D_IN) ? xr[c] : 0.f;
            vals[i] = v; s += v; sq += v * v;
        }
        s += __shfl_xor(s, 1);  s += __shfl_xor(s, 2);
        sq += __shfl_xor(sq, 1); sq += __shfl_xor(sq, 2);
        float mean = s * (1.f / 153.f);
        float var = sq * (1.f / 153.f) - mean * mean;
        float rstd = rsqrtf(var + 1e-5f);
        #pragma unroll
        for (int i = 0; i < 39; i++) {
            int c = seg + i * 4;
            if (c < D_IN) {
                float v = (vals[i] - mean) * rstd * ln_in_g[c] + ln_in_b[c];
                xb[r * XB_STRIDE + c] = f2h(v);
            }
        }
        if (tid < M_TILE) {
            #pragma unroll
            for (int c = D_IN; c < XB_STRIDE; c++) xb[tid * XB_STRIDE + c] = 0;
        }
    }
    __syncthreads();  // B1: xb ready

    // ---- Phase 2: x_proj = relu(x_norm @ Wp + bp) + x_norm (M=160 cols, N=64 rows, K=160)
    // swapped: wave w owns col-tiles ct = w + 4q
    {
        const int nnt = (wave < 2) ? 3 : 2;
        f32x4 acc[3][4];
        #pragma unroll
        for (int q = 0; q < 3; q++)
            #pragma unroll
            for (int rt = 0; rt < 4; rt++) acc[q][rt] = fzero;
        #pragma unroll
        for (int kt = 0; kt < 5; kt++) {
            f16x8 a0 = ldsA(xb, XB_STRIDE, 0,  kt * 32, lane);
            f16x8 a1 = ldsA(xb, XB_STRIDE, 16, kt * 32, lane);
            f16x8 a2 = ldsA(xb, XB_STRIDE, 32, kt * 32, lane);
            f16x8 a3 = ldsA(xb, XB_STRIDE, 48, kt * 32, lane);
            #pragma unroll
            for (int q = 0; q < 3; q++) {
                if (q < nnt) {
                    int ct = wave + 4 * q;
                    f16x8 p = ldB(wsw, (OFF_WP >> 9) + kt * 10 + ct, lane);
                    acc[q][0] = mfma16(p, a0, acc[q][0]);
                    acc[q][1] = mfma16(p, a1, acc[q][1]);
                    acc[q][2] = mfma16(p, a2, acc[q][2]);
                    acc[q][3] = mfma16(p, a3, acc[q][3]);
                }
            }
        }
        #pragma unroll
        for (int q = 0; q < 3; q++) {
            if (q < nnt) {
                int colb = (wave + 4 * q) * 16 + quad * 4;
                float bpv[4];
                #pragma unroll
                for (int i = 0; i < 4; i++) {
                    int c = colb + i;
                    bpv[i] = (c < D_IN) ? bp[c] : 0.f;
                }
                #pragma unroll
                for (int rt = 0; rt < 4; rt++) {
                    int row = rt * 16 + nl;
                    u32x2 rv = *(const u32x2*)(xb + row * XB_STRIDE + colb);
                    float r0 = h2f((unsigned short)(rv[0] & 0xffff));
                    float r1 = h2f((unsigned short)(rv[0] >> 16));
                    float r2 = h2f((unsigned short)(rv[1] & 0xffff));
                    float r3 = h2f((unsigned short)(rv[1] >> 16));
                    float v0 = fmaxf(acc[q][rt][0] + bpv[0], 0.f) + r0;
                    float v1 = fmaxf(acc[q][rt][1] + bpv[1], 0.f) + r1;
                    float v2 = fmaxf(acc[q][rt][2] + bpv[2], 0.f) + r2;
                    float v3 = fmaxf(acc[q][rt][3] + bpv[3], 0.f) + r3;
                    u32x2 w; w[0] = pk2(v0, v1); w[1] = pk2(v2, v3);
                    *(u32x2*)(xp + row * XB_STRIDE + colb) = w;
                }
            }
        }
    }
    __syncthreads();  // B2: xp ready; xb dead -> U reusable as g1h

    // ---- Hoist xp fragments into registers (shared by phase 3 + all experts)
    f16x8 xpf[4][5];
    #pragma unroll
    for (int rt = 0; rt < 4; rt++)
        #pragma unroll
        for (int kt = 0; kt < 5; kt++)
            xpf[rt][kt] = ldsA(xp, XB_STRIDE, rt * 16, kt * 32, lane);

    // ---- Phase 3: g1 = relu(x_proj @ Wg1 + bg1)  (M=64 cols, N=64 rows, K=160)
    {
        f32x4 acc[4];
        #pragma unroll
        for (int rt = 0; rt < 4; rt++) acc[rt] = fzero;
        #pragma unroll
        for (int kt = 0; kt < 5; kt++) {
            f16x8 p = ldB(wsw, (OFF_WG1 >> 9) + kt * 4 + wave, lane);
            #pragma unroll
            for (int rt = 0; rt < 4; rt++)
                acc[rt] = mfma16(p, xpf[rt][kt], acc[rt]);
        }
        int colb = wave * 16 + quad * 4;
        f32x4 bv = *(const f32x4*)(bg1 + colb);
        #pragma unroll
        for (int rt = 0; rt < 4; rt++) {
            int row = rt * 16 + nl;
            stRelu4(g1h + row * G1H_STRIDE + colb, acc[rt], bv);
        }
    }
    __syncthreads();  // B3: g1h ready

    // ---- Phase 4: g2 = relu(g1 @ Wg2 + bg2)  (M=32 cols, N=64 rows, K=64)
    {
        int ct = wave & 1;
        int rtb = (wave >> 1) * 2;
        f32x4 acc[2] = {fzero, fzero};
        #pragma unroll
        for (int kt = 0; kt < 2; kt++) {
            f16x8 p = ldB(wsw, (OFF_WG2 >> 9) + kt * 2 + ct, lane);
            #pragma unroll
            for (int r = 0; r < 2; r++) {
                f16x8 a = ldsA(g1h, G1H_STRIDE, (rtb + r) * 16, kt * 32, lane);
                acc[r] = mfma16(p, a, acc[r]);
            }
        }
        int colb = ct * 16 + quad * 4;
        f32x4 bv = *(const f32x4*)(bg2 + colb);
        #pragma unroll
        for (int r = 0; r < 2; r++) {
            int row = (rtb + r) * 16 + nl;
            stRelu4(g2s + row * G2S_STRIDE + colb, acc[r], bv);
        }
    }
    __syncthreads();  // B4a: g2s ready

    // ---- Phase 5: logits = g2 @ Wg3 + bg3 + softmax (M=16(8) cols, N=64 rows, K=32)
    {
        f16x8 a = ldsA(g2s, G2S_STRIDE, wave * 16, 0, lane);
        f16x8 p = ldB(wsw, (OFF_WG3 >> 9), lane);
        f32x4 lg = mfma16(p, a, fzero);
        f32x4 bv = fzero;
        if (quad < 2) bv = *(const f32x4*)(bg3 + quad * 4);
        float l0 = lg[0] + bv[0], l1 = lg[1] + bv[1];
        float l2 = lg[2] + bv[2], l3 = lg[3] + bv[3];
        float m4 = fmaxf(fmaxf(l0, l1), fmaxf(l2, l3));
        float m8 = fmaxf(m4, __shfl_xor(m4, 16));   // quad0<->quad1 (rows match)
        float e0 = __expf(l0 - m8), e1 = __expf(l1 - m8);
        float e2 = __expf(l2 - m8), e3 = __expf(l3 - m8);
        float s4 = (e0 + e1) + (e2 + e3);
        float s8 = s4 + __shfl_xor(s4, 16);
        float inv = 1.f / s8;
        if (quad < 2) {
            int row = wave * 16 + nl;
            f32x4 g = {e0 * inv, e1 * inv, e2 * inv, e3 * inv};
            *(f32x4*)(gate + row * 8 + quad * 4) = g;
            *(f32x4*)(out + (size_t)B_ROWS * 8 + (rowBase + row) * 8 + quad * 4) = g;
        }
    }
    __syncthreads();  // B4: gate ready; U region free for h1/h2

    // ---- Phase 6: experts (2 barriers per expert) ----
    float oacc[4] = {0.f, 0.f, 0.f, 0.f};
    for (int e = 0; e < 8; e++) {
        // We1: h1 = relu(x_proj @ We1[e] + be1[e])  (M=128 cols, N=64 rows, K=160)
        {
            f32x4 acc[2][4];
            #pragma unroll
            for (int q = 0; q < 2; q++)
                #pragma unroll
                for (int rt = 0; rt < 4; rt++) acc[q][rt] = fzero;
            #pragma unroll
            for (int kt = 0; kt < 5; kt++) {
                int tb = (OFF_WE1 >> 9) + (e * 5 + kt) * 8 + wave * 2;
                f16x8 p0 = ldB(wsw, tb, lane);
                f16x8 p1 = ldB(wsw, tb + 1, lane);
                #pragma unroll
                for (int rt = 0; rt < 4; rt++) {
                    acc[0][rt] = mfma16(p0, xpf[rt][kt], acc[0][rt]);
                    acc[1][rt] = mfma16(p1, xpf[rt][kt], acc[1][rt]);
                }
            }
            #pragma unroll
            for (int q = 0; q < 2; q++) {
                int colb = (wave * 2 + q) * 16 + quad * 4;
                f32x4 bv = *(const f32x4*)(be1 + e * 128 + colb);
                #pragma unroll
                for (int rt = 0; rt < 4; rt++) {
                    int row = rt * 16 + nl;
                    stRelu4(h1 + row * H1_STRIDE + colb, acc[q][rt], bv);
                }
            }
        }
        __syncthreads();  // Be1: h1 ready (also orders prev We3 h2-reads before h2-writes)
        // We2: h2 = relu(h1 @ We2[e] + be2[e])  (M=64 cols, N=64 rows, K=128)
        {
            f32x4 acc[4];
            #pragma unroll
            for (int rt = 0; rt < 4; rt++) acc[rt] = fzero;
            #pragma unroll
            for (int kt = 0; kt < 4; kt++) {
                f16x8 p = ldB(wsw, (OFF_WE2 >> 9) + (e * 4 + kt) * 4 + wave, lane);
                #pragma unroll
                for (int rt = 0; rt < 4; rt++) {
                    f16x8 a = ldsA(h1, H1_STRIDE, rt * 16, kt * 32, lane);
                    acc[rt] = mfma16(p, a, acc[rt]);
                }
            }
            int colb = wave * 16 + quad * 4;
            f32x4 bv = *(const f32x4*)(be2 + e * 64 + colb);
            #pragma unroll
            for (int rt = 0; rt < 4; rt++) {
                int row = rt * 16 + nl;
                stRelu4(h2 + row * H2_STRIDE + colb, acc[rt], bv);
            }
        }
        __syncthreads();  // Be2: h2 ready (also orders all h1-reads before next h1-writes)
        // We3 + gated accumulate (M=16(8) cols, N-tile = wave's 16 rows, K=64)
        {
            f32x4 acc = fzero;
            #pragma unroll
            for (int kt = 0; kt < 2; kt++) {
                f16x8 p = ldB(wsw, (OFF_WE3 >> 9) + e * 2 + kt, lane);
                f16x8 a = ldsA(h2, H2_STRIDE, wave * 16, kt * 32, lane);
                acc = mfma16(p, a, acc);
            }
            if (quad < 2) {  // cols quad*4..quad*4+3 (cols 8..15 are padding)
                int row = wave * 16 + nl;
                f32x4 bv = *(const f32x4*)(be3 + e * 8 + quad * 4);
                float g = gate[row * 8 + e];
                #pragma unroll
                for (int i = 0; i < 4; i++) oacc[i] += g * (acc[i] + bv[i]);
            }
        }
        // (no end-of-loop barrier: h1 WAR covered by Be2, h2 WAR by next Be1)
    }

    // ---- Phase 7: output LayerNorm over 8 + float4 store ----
    {
        float s4 = (oacc[0] + oacc[1]) + (oacc[2] + oacc[3]);
        float q4 = oacc[0] * oacc[0] + oacc[1] * oacc[1]
                 + oacc[2] * oacc[2] + oacc[3] * oacc[3];
        float s8 = s4 + __shfl_xor(s4, 16);   // quad0<->quad1 combine (quads 2,3 are zeros)
        float q8 = q4 + __shfl_xor(q4, 16);
        float mean = s8 * 0.125f;
        float var = q8 * 0.125f - mean * mean;
        float rstd = rsqrtf(var + 1e-5f);
        if (quad < 2) {
            f32x4 go = *(const f32x4*)(ln_out_g + quad * 4);
            f32x4 bo = *(const f32x4*)(ln_out_b + quad * 4);
            f32x4 ov;
            #pragma unroll
            for (int i = 0; i < 4; i++)
                ov[i] = (oacc[i] - mean) * rstd * go[i] + bo[i];
            size_t row = rowBase + wave * 16 + nl;
            *(f32x4*)(out + row * 8 + quad * 4) = ov;
        }
    }
}

extern "C" void kernel_launch(void* const* d_in, const int* in_sizes, int n_in,
                              void* d_out, int out_size, void* d_ws, size_t ws_size,
                              hipStream_t stream) {
    const float* x        = (const float*)d_in[0];
    const float* ln_in_g  = (const float*)d_in[1];
    const float* ln_in_b  = (const float*)d_in[2];
    const float* Wp       = (const float*)d_in[3];
    const float* bp       = (const float*)d_in[4];
    const float* Wg1      = (const float*)d_in[5];
    const float* bg1      = (const float*)d_in[6];
    const float* Wg2      = (const float*)d_in[7];
    const float* bg2      = (const float*)d_in[8];
    const float* Wg3      = (const float*)d_in[9];
    const float* bg3      = (const float*)d_in[10];
    const float* We1      = (const float*)d_in[11];
    const float* be1      = (const float*)d_in[12];
    const float* We2      = (const float*)d_in[13];
    const float* be2      = (const float*)d_in[14];
    const float* We3      = (const float*)d_in[15];
    const float* be3      = (const float*)d_in[16];
    const float* ln_out_g = (const float*)d_in[17];
    const float* ln_out_b = (const float*)d_in[18];
    unsigned short* ws = (unsigned short*)d_ws;
    float* out = (float*)d_out;

    convert_weights<<<(TOTAL_W + 255) / 256, 256, 0, stream>>>(
        Wp, Wg1, We1, We2, We3, Wg2, Wg3, ws);
    moe_main<<<B_ROWS / M_TILE, 256, 0, stream>>>(
        x, ln_in_g, ln_in_b, bp, bg1, bg2, bg3,
        be1, be2, be3, ln_out_g, ln_out_b, ws, out);
}

// Round 2
// 463.801 us; speedup vs baseline: 1.0047x; 1.0047x over previous
//
#include <hip/hip_runtime.h>
#include <stdint.h>
#include <stddef.h>

typedef __attribute__((ext_vector_type(8))) _Float16 f16x8;
typedef __attribute__((ext_vector_type(4))) float f32x4;
typedef __attribute__((ext_vector_type(2))) unsigned int u32x2;

#define D_IN 153
#define B_ROWS 262144
#define M_TILE 64
#define XB_STRIDE 168   // 336 B rows (mult of 16 B)
#define G1H_STRIDE 72   // 144 B rows (mult of 16 B)
#define H1_STRIDE 136   // 272 B rows
#define H2_STRIDE 72    // 144 B rows
#define G2S_STRIDE 40   // 80 B rows (mult of 16 B)

// swizzled f16 weight layout offsets (in u16 elements, all multiples of 512)
#define OFF_WP 0
#define SZ_WP (5*10*512)
#define OFF_WG1 (OFF_WP + SZ_WP)
#define SZ_WG1 (5*4*512)
#define OFF_WE1 (OFF_WG1 + SZ_WG1)
#define SZ_WE1 (8*5*8*512)
#define OFF_WE2 (OFF_WE1 + SZ_WE1)
#define SZ_WE2 (8*4*4*512)
#define OFF_WE3 (OFF_WE2 + SZ_WE2)
#define SZ_WE3 (8*2*512)
#define OFF_WG2 (OFF_WE3 + SZ_WE3)
#define SZ_WG2 (2*2*512)
#define OFF_WG3 (OFF_WG2 + SZ_WG2)
#define SZ_WG3 (1*512)
#define TOTAL_W (OFF_WG3 + SZ_WG3)   // 275968 u16 = 551936 B

__device__ __forceinline__ unsigned short f2h(float f) {
    _Float16 h = (_Float16)f;                 // v_cvt_f16_f32, RNE
    union { _Float16 h; unsigned short u; } v; v.h = h;
    return v.u;
}
__device__ __forceinline__ float h2f(unsigned short u) {
    union { unsigned short u; _Float16 h; } v; v.u = u;
    return (float)v.h;
}
__device__ __forceinline__ unsigned int pk2(float a, float b) {
    return (unsigned int)f2h(a) | ((unsigned int)f2h(b) << 16);
}

__device__ __forceinline__ f32x4 mfma16(f16x8 a, f16x8 b, f32x4 c) {
    return __builtin_amdgcn_mfma_f32_16x16x32_f16(a, b, c, 0, 0, 0);
}

// Activation fragment from LDS (works as A- OR B-operand: lane&15 -> row,
// quad -> k-octet). 16B contiguous per lane.
__device__ __forceinline__ f16x8 ldsA(const unsigned short* buf, int stride,
                                      int m0, int k0, int lane) {
    int row = m0 + (lane & 15);
    int col = k0 + (lane >> 4) * 8;
    return *(const f16x8*)(buf + row * stride + col);
}
// Weight fragment from pre-swizzled global: tile of 64 lanes x 16B
__device__ __forceinline__ f16x8 ldB(const unsigned short* ws, int tile, int lane) {
    return *(const f16x8*)(ws + (size_t)tile * 512 + lane * 8);
}

// relu(acc+bias) -> 4 packed f16 (4 consecutive cols) -> one ds_write_b64
__device__ __forceinline__ void stRelu4(unsigned short* dst, const f32x4 a, const f32x4 bv) {
    float v0 = fmaxf(a[0] + bv[0], 0.f);
    float v1 = fmaxf(a[1] + bv[1], 0.f);
    float v2 = fmaxf(a[2] + bv[2], 0.f);
    float v3 = fmaxf(a[3] + bv[3], 0.f);
    u32x2 w; w[0] = pk2(v0, v1); w[1] = pk2(v2, v3);
    *(u32x2*)dst = w;
}

// ---------------------------------------------------------------------------
// Weight conversion: fp32 -> fp16 in MFMA fragment-swizzled layout.
// ---------------------------------------------------------------------------
__global__ __launch_bounds__(256) void convert_weights(
        const float* __restrict__ Wp, const float* __restrict__ Wg1,
        const float* __restrict__ We1, const float* __restrict__ We2,
        const float* __restrict__ We3, const float* __restrict__ Wg2,
        const float* __restrict__ Wg3, unsigned short* __restrict__ ws) {
    int idx = blockIdx.x * 256 + threadIdx.x;
    if (idx >= TOTAL_W) return;
    int j = idx & 7;
    int lane = (idx >> 3) & 63;
    int t = idx >> 9;
    int quad = lane >> 4, nl = lane & 15;
    int kin = quad * 8 + j;
    float val = 0.f;
    if (idx < OFF_WG1) {                 // Wp [153][153], Kp=160 Np=160
        int kt = t / 10, nt = t % 10;
        int k = kt * 32 + kin, n = nt * 16 + nl;
        if (k < 153 && n < 153) val = Wp[k * 153 + n];
    } else if (idx < OFF_WE1) {          // Wg1 [153][64]
        int tt = t - (OFF_WG1 >> 9);
        int kt = tt / 4, nt = tt % 4;
        int k = kt * 32 + kin, n = nt * 16 + nl;
        if (k < 153) val = Wg1[k * 64 + n];
    } else if (idx < OFF_WE2) {          // We1 [8][153][128]
        int tt = t - (OFF_WE1 >> 9);
        int e = tt / 40, r = tt % 40, kt = r / 8, nt = r % 8;
        int k = kt * 32 + kin, n = nt * 16 + nl;
        if (k < 153) val = We1[((size_t)e * 153 + k) * 128 + n];
    } else if (idx < OFF_WE3) {          // We2 [8][128][64]
        int tt = t - (OFF_WE2 >> 9);
        int e = tt / 16, r = tt % 16, kt = r / 4, nt = r % 4;
        int k = kt * 32 + kin, n = nt * 16 + nl;
        val = We2[((size_t)e * 128 + k) * 64 + n];
    } else if (idx < OFF_WG2) {          // We3 [8][64][8], Np=16 (cols 8..15 zero)
        int tt = t - (OFF_WE3 >> 9);
        int e = tt / 2, kt = tt % 2;
        int k = kt * 32 + kin, n = nl;
        if (n < 8) val = We3[((size_t)e * 64 + k) * 8 + n];
    } else if (idx < OFF_WG3) {          // Wg2 [64][32]
        int tt = t - (OFF_WG2 >> 9);
        int kt = tt >> 1, nt = tt & 1;
        int k = kt * 32 + kin, n = nt * 16 + nl;
        val = Wg2[k * 32 + n];
    } else {                             // Wg3 [32][8] (cols 8..15 zero)
        int k = kin, n = nl;
        if (n < 8) val = Wg3[k * 8 + n];
    }
    ws[idx] = f2h(val);
}

// ---------------------------------------------------------------------------
// Fused MoE kernel. Change vs R1 (284us): the 20 hoisted xp fragments are
// 20 individually-NAMED f16x8 variables (not an array) with macro-expanded
// static uses, so regalloc actually keeps them resident (R1: VGPR_Count=84
// proved the 80-VGPR array was spilled/rematerialized). Budget: 80 (xpf) +
// 32 (We1 accs) + ~30 misc < 170 (= 512/3 at __launch_bounds__(256,3)).
// ---------------------------------------------------------------------------
__global__ __launch_bounds__(256, 3) void moe_main(
        const float* __restrict__ x,
        const float* __restrict__ ln_in_g, const float* __restrict__ ln_in_b,
        const float* __restrict__ bp,
        const float* __restrict__ bg1, const float* __restrict__ bg2,
        const float* __restrict__ bg3,
        const float* __restrict__ be1, const float* __restrict__ be2,
        const float* __restrict__ be3,
        const float* __restrict__ ln_out_g, const float* __restrict__ ln_out_b,
        const unsigned short* __restrict__ wsw,
        float* __restrict__ out) {
    const int tid = threadIdx.x;
    const int wave = tid >> 6, lane = tid & 63;
    const int quad = lane >> 4, nl = lane & 15;
    const size_t rowBase = (size_t)blockIdx.x * M_TILE;

    __shared__ __align__(16) char U[26624];  // xb -> g1h/g2s -> h1|h2
    __shared__ __align__(16) unsigned short xp[M_TILE * XB_STRIDE];  // x_proj f16
    __shared__ __align__(16) float gate[M_TILE * 8];
    unsigned short* xb  = (unsigned short*)U;              // [64][168] f16
    unsigned short* g1h = (unsigned short*)U;              // [64][72]  f16 (9216 B)
    unsigned short* g2s = (unsigned short*)(U + 17408);    // [64][40]  f16 (5120 B)
    unsigned short* h1  = (unsigned short*)U;              // [64][136] f16
    unsigned short* h2  = (unsigned short*)(U + 17408);    // [64][72]  f16

    const f32x4 fzero = {0.f, 0.f, 0.f, 0.f};

    // ---- Phase 1: input LayerNorm (4 threads per row) ----
    {
        int r = tid >> 2, seg = tid & 3;
        const float* xr = x + (rowBase + r) * (size_t)D_IN;
        float vals[39];
        float s = 0.f, sq = 0.f;
        #pragma unroll
        for (int i = 0; i < 39; i++) {
            int c = seg + i * 4;
            float v = (c < D_IN) ? xr[c] : 0.f;
            vals[i] = v; s += v; sq += v * v;
        }
        s += __shfl_xor(s, 1);  s += __shfl_xor(s, 2);
        sq += __shfl_xor(sq, 1); sq += __shfl_xor(sq, 2);
        float mean = s * (1.f / 153.f);
        float var = sq * (1.f / 153.f) - mean * mean;
        float rstd = rsqrtf(var + 1e-5f);
        #pragma unroll
        for (int i = 0; i < 39; i++) {
            int c = seg + i * 4;
            if (c < D_IN) {
                float v = (vals[i] - mean) * rstd * ln_in_g[c] + ln_in_b[c];
                xb[r * XB_STRIDE + c] = f2h(v);
            }
        }
        if (tid < M_TILE) {
            #pragma unroll
            for (int c = D_IN; c < XB_STRIDE; c++) xb[tid * XB_STRIDE + c] = 0;
        }
    }
    __syncthreads();  // B1: xb ready

    // ---- Phase 2: x_proj = relu(x_norm @ Wp + bp) + x_norm (M=160 cols, N=64 rows, K=160)
    {
        const int nnt = (wave < 2) ? 3 : 2;
        f32x4 acc[3][4];
        #pragma unroll
        for (int q = 0; q < 3; q++)
            #pragma unroll
            for (int rt = 0; rt < 4; rt++) acc[q][rt] = fzero;
        #pragma unroll
        for (int kt = 0; kt < 5; kt++) {
            f16x8 a0 = ldsA(xb, XB_STRIDE, 0,  kt * 32, lane);
            f16x8 a1 = ldsA(xb, XB_STRIDE, 16, kt * 32, lane);
            f16x8 a2 = ldsA(xb, XB_STRIDE, 32, kt * 32, lane);
            f16x8 a3 = ldsA(xb, XB_STRIDE, 48, kt * 32, lane);
            #pragma unroll
            for (int q = 0; q < 3; q++) {
                if (q < nnt) {
                    int ct = wave + 4 * q;
                    f16x8 p = ldB(wsw, (OFF_WP >> 9) + kt * 10 + ct, lane);
                    acc[q][0] = mfma16(p, a0, acc[q][0]);
                    acc[q][1] = mfma16(p, a1, acc[q][1]);
                    acc[q][2] = mfma16(p, a2, acc[q][2]);
                    acc[q][3] = mfma16(p, a3, acc[q][3]);
                }
            }
        }
        #pragma unroll
        for (int q = 0; q < 3; q++) {
            if (q < nnt) {
                int colb = (wave + 4 * q) * 16 + quad * 4;
                float bpv[4];
                #pragma unroll
                for (int i = 0; i < 4; i++) {
                    int c = colb + i;
                    bpv[i] = (c < D_IN) ? bp[c] : 0.f;
                }
                #pragma unroll
                for (int rt = 0; rt < 4; rt++) {
                    int row = rt * 16 + nl;
                    u32x2 rv = *(const u32x2*)(xb + row * XB_STRIDE + colb);
                    float r0 = h2f((unsigned short)(rv[0] & 0xffff));
                    float r1 = h2f((unsigned short)(rv[0] >> 16));
                    float r2 = h2f((unsigned short)(rv[1] & 0xffff));
                    float r3 = h2f((unsigned short)(rv[1] >> 16));
                    float v0 = fmaxf(acc[q][rt][0] + bpv[0], 0.f) + r0;
                    float v1 = fmaxf(acc[q][rt][1] + bpv[1], 0.f) + r1;
                    float v2 = fmaxf(acc[q][rt][2] + bpv[2], 0.f) + r2;
                    float v3 = fmaxf(acc[q][rt][3] + bpv[3], 0.f) + r3;
                    u32x2 w; w[0] = pk2(v0, v1); w[1] = pk2(v2, v3);
                    *(u32x2*)(xp + row * XB_STRIDE + colb) = w;
                }
            }
        }
    }
    __syncthreads();  // B2: xp ready; xb dead -> U reusable as g1h

    // ---- Hoist xp fragments into 20 NAMED registers (80 VGPR) ----
    f16x8 xpf00, xpf01, xpf02, xpf03, xpf04;
    f16x8 xpf10, xpf11, xpf12, xpf13, xpf14;
    f16x8 xpf20, xpf21, xpf22, xpf23, xpf24;
    f16x8 xpf30, xpf31, xpf32, xpf33, xpf34;
    #define LOAD_XPF(rt) \
        xpf##rt##0 = ldsA(xp, XB_STRIDE, rt * 16, 0,   lane); \
        xpf##rt##1 = ldsA(xp, XB_STRIDE, rt * 16, 32,  lane); \
        xpf##rt##2 = ldsA(xp, XB_STRIDE, rt * 16, 64,  lane); \
        xpf##rt##3 = ldsA(xp, XB_STRIDE, rt * 16, 96,  lane); \
        xpf##rt##4 = ldsA(xp, XB_STRIDE, rt * 16, 128, lane);
    LOAD_XPF(0) LOAD_XPF(1) LOAD_XPF(2) LOAD_XPF(3)
    #undef LOAD_XPF

    // ---- Phase 3: g1 = relu(x_proj @ Wg1 + bg1)  (M=64 cols, N=64 rows, K=160)
    {
        f32x4 acc0 = fzero, acc1 = fzero, acc2 = fzero, acc3 = fzero;
        #define PH3(kt) { \
            f16x8 p = ldB(wsw, (OFF_WG1 >> 9) + kt * 4 + wave, lane); \
            acc0 = mfma16(p, xpf0##kt, acc0); \
            acc1 = mfma16(p, xpf1##kt, acc1); \
            acc2 = mfma16(p, xpf2##kt, acc2); \
            acc3 = mfma16(p, xpf3##kt, acc3); }
        PH3(0) PH3(1) PH3(2) PH3(3) PH3(4)
        #undef PH3
        int colb = wave * 16 + quad * 4;
        f32x4 bv = *(const f32x4*)(bg1 + colb);
        stRelu4(g1h + (0 * 16 + nl) * G1H_STRIDE + colb, acc0, bv);
        stRelu4(g1h + (1 * 16 + nl) * G1H_STRIDE + colb, acc1, bv);
        stRelu4(g1h + (2 * 16 + nl) * G1H_STRIDE + colb, acc2, bv);
        stRelu4(g1h + (3 * 16 + nl) * G1H_STRIDE + colb, acc3, bv);
    }
    __syncthreads();  // B3: g1h ready

    // ---- Phase 4: g2 = relu(g1 @ Wg2 + bg2)  (M=32 cols, N=64 rows, K=64)
    {
        int ct = wave & 1;
        int rtb = (wave >> 1) * 2;
        f32x4 acc[2] = {fzero, fzero};
        #pragma unroll
        for (int kt = 0; kt < 2; kt++) {
            f16x8 p = ldB(wsw, (OFF_WG2 >> 9) + kt * 2 + ct, lane);
            #pragma unroll
            for (int r = 0; r < 2; r++) {
                f16x8 a = ldsA(g1h, G1H_STRIDE, (rtb + r) * 16, kt * 32, lane);
                acc[r] = mfma16(p, a, acc[r]);
            }
        }
        int colb = ct * 16 + quad * 4;
        f32x4 bv = *(const f32x4*)(bg2 + colb);
        #pragma unroll
        for (int r = 0; r < 2; r++) {
            int row = (rtb + r) * 16 + nl;
            stRelu4(g2s + row * G2S_STRIDE + colb, acc[r], bv);
        }
    }
    __syncthreads();  // B4a: g2s ready

    // ---- Phase 5: logits = g2 @ Wg3 + bg3 + softmax (M=16(8) cols, N=64 rows, K=32)
    {
        f16x8 a = ldsA(g2s, G2S_STRIDE, wave * 16, 0, lane);
        f16x8 p = ldB(wsw, (OFF_WG3 >> 9), lane);
        f32x4 lg = mfma16(p, a, fzero);
        f32x4 bv = fzero;
        if (quad < 2) bv = *(const f32x4*)(bg3 + quad * 4);
        float l0 = lg[0] + bv[0], l1 = lg[1] + bv[1];
        float l2 = lg[2] + bv[2], l3 = lg[3] + bv[3];
        float m4 = fmaxf(fmaxf(l0, l1), fmaxf(l2, l3));
        float m8 = fmaxf(m4, __shfl_xor(m4, 16));   // quad0<->quad1 (rows match)
        float e0 = __expf(l0 - m8), e1 = __expf(l1 - m8);
        float e2 = __expf(l2 - m8), e3 = __expf(l3 - m8);
        float s4 = (e0 + e1) + (e2 + e3);
        float s8 = s4 + __shfl_xor(s4, 16);
        float inv = 1.f / s8;
        if (quad < 2) {
            int row = wave * 16 + nl;
            f32x4 g = {e0 * inv, e1 * inv, e2 * inv, e3 * inv};
            *(f32x4*)(gate + row * 8 + quad * 4) = g;
            *(f32x4*)(out + (size_t)B_ROWS * 8 + (rowBase + row) * 8 + quad * 4) = g;
        }
    }
    __syncthreads();  // B4: gate ready; U region free for h1/h2

    // ---- Phase 6: experts (2 barriers per expert) ----
    float oacc[4] = {0.f, 0.f, 0.f, 0.f};
    for (int e = 0; e < 8; e++) {
        // We1: h1 = relu(x_proj @ We1[e] + be1[e])  (M=128 cols, N=64 rows, K=160)
        {
            f32x4 c00 = fzero, c01 = fzero, c02 = fzero, c03 = fzero;
            f32x4 c10 = fzero, c11 = fzero, c12 = fzero, c13 = fzero;
            const int tbase = (OFF_WE1 >> 9) + e * 40 + wave * 2;
            #define WE1(kt) { \
                f16x8 p0 = ldB(wsw, tbase + kt * 8, lane); \
                f16x8 p1 = ldB(wsw, tbase + kt * 8 + 1, lane); \
                c00 = mfma16(p0, xpf0##kt, c00); \
                c01 = mfma16(p0, xpf1##kt, c01); \
                c02 = mfma16(p0, xpf2##kt, c02); \
                c03 = mfma16(p0, xpf3##kt, c03); \
                c10 = mfma16(p1, xpf0##kt, c10); \
                c11 = mfma16(p1, xpf1##kt, c11); \
                c12 = mfma16(p1, xpf2##kt, c12); \
                c13 = mfma16(p1, xpf3##kt, c13); }
            WE1(0) WE1(1) WE1(2) WE1(3) WE1(4)
            #undef WE1
            {
                int colb = (wave * 2 + 0) * 16 + quad * 4;
                f32x4 bv = *(const f32x4*)(be1 + e * 128 + colb);
                stRelu4(h1 + (0 * 16 + nl) * H1_STRIDE + colb, c00, bv);
                stRelu4(h1 + (1 * 16 + nl) * H1_STRIDE + colb, c01, bv);
                stRelu4(h1 + (2 * 16 + nl) * H1_STRIDE + colb, c02, bv);
                stRelu4(h1 + (3 * 16 + nl) * H1_STRIDE + colb, c03, bv);
            }
            {
                int colb = (wave * 2 + 1) * 16 + quad * 4;
                f32x4 bv = *(const f32x4*)(be1 + e * 128 + colb);
                stRelu4(h1 + (0 * 16 + nl) * H1_STRIDE + colb, c10, bv);
                stRelu4(h1 + (1 * 16 + nl) * H1_STRIDE + colb, c11, bv);
                stRelu4(h1 + (2 * 16 + nl) * H1_STRIDE + colb, c12, bv);
                stRelu4(h1 + (3 * 16 + nl) * H1_STRIDE + colb, c13, bv);
            }
        }
        __syncthreads();  // Be1: h1 ready (also orders prev We3 h2-reads before h2-writes)
        // We2: h2 = relu(h1 @ We2[e] + be2[e])  (M=64 cols, N=64 rows, K=128)
        {
            f32x4 acc[4];
            #pragma unroll
            for (int rt = 0; rt < 4; rt++) acc[rt] = fzero;
            #pragma unroll
            for (int kt = 0; kt < 4; kt++) {
                f16x8 p = ldB(wsw, (OFF_WE2 >> 9) + (e * 4 + kt) * 4 + wave, lane);
                #pragma unroll
                for (int rt = 0; rt < 4; rt++) {
                    f16x8 a = ldsA(h1, H1_STRIDE, rt * 16, kt * 32, lane);
                    acc[rt] = mfma16(p, a, acc[rt]);
                }
            }
            int colb = wave * 16 + quad * 4;
            f32x4 bv = *(const f32x4*)(be2 + e * 64 + colb);
            #pragma unroll
            for (int rt = 0; rt < 4; rt++) {
                int row = rt * 16 + nl;
                stRelu4(h2 + row * H2_STRIDE + colb, acc[rt], bv);
            }
        }
        __syncthreads();  // Be2: h2 ready (also orders all h1-reads before next h1-writes)
        // We3 + gated accumulate (M=16(8) cols, N-tile = wave's 16 rows, K=64)
        {
            f32x4 acc = fzero;
            #pragma unroll
            for (int kt = 0; kt < 2; kt++) {
                f16x8 p = ldB(wsw, (OFF_WE3 >> 9) + e * 2 + kt, lane);
                f16x8 a = ldsA(h2, H2_STRIDE, wave * 16, kt * 32, lane);
                acc = mfma16(p, a, acc);
            }
            if (quad < 2) {  // cols quad*4..quad*4+3 (cols 8..15 are padding)
                int row = wave * 16 + nl;
                f32x4 bv = *(const f32x4*)(be3 + e * 8 + quad * 4);
                float g = gate[row * 8 + e];
                #pragma unroll
                for (int i = 0; i < 4; i++) oacc[i] += g * (acc[i] + bv[i]);
            }
        }
        // (no end-of-loop barrier: h1 WAR covered by Be2, h2 WAR by next Be1)
    }

    // ---- Phase 7: output LayerNorm over 8 + float4 store ----
    {
        float s4 = (oacc[0] + oacc[1]) + (oacc[2] + oacc[3]);
        float q4 = oacc[0] * oacc[0] + oacc[1] * oacc[1]
                 + oacc[2] * oacc[2] + oacc[3] * oacc[3];
        float s8 = s4 + __shfl_xor(s4, 16);   // quad0<->quad1 combine (quads 2,3 are zeros)
        float q8 = q4 + __shfl_xor(q4, 16);
        float mean = s8 * 0.125f;
        float var = q8 * 0.125f - mean * mean;
        float rstd = rsqrtf(var + 1e-5f);
        if (quad < 2) {
            f32x4 go = *(const f32x4*)(ln_out_g + quad * 4);
            f32x4 bo = *(const f32x4*)(ln_out_b + quad * 4);
            f32x4 ov;
            #pragma unroll
            for (int i = 0; i < 4; i++)
                ov[i] = (oacc[i] - mean) * rstd * go[i] + bo[i];
            size_t row = rowBase + wave * 16 + nl;
            *(f32x4*)(out + row * 8 + quad * 4) = ov;
        }
    }
}

extern "C" void kernel_launch(void* const* d_in, const int* in_sizes, int n_in,
                              void* d_out, int out_size, void* d_ws, size_t ws_size,
                              hipStream_t stream) {
    const float* x        = (const float*)d_in[0];
    const float* ln_in_g  = (const float*)d_in[1];
    const float* ln_in_b  = (const float*)d_in[2];
    const float* Wp       = (const float*)d_in[3];
    const float* bp       = (const float*)d_in[4];
    const float* Wg1      = (const float*)d_in[5];
    const float* bg1      = (const float*)d_in[6];
    const float* Wg2      = (const float*)d_in[7];
    const float* bg2      = (const float*)d_in[8];
    const float* Wg3      = (const float*)d_in[9];
    const float* bg3      = (const float*)d_in[10];
    const float* We1      = (const float*)d_in[11];
    const float* be1      = (const float*)d_in[12];
    const float* We2      = (const float*)d_in[13];
    const float* be2      = (const float*)d_in[14];
    const float* We3      = (const float*)d_in[15];
    const float* be3      = (const float*)d_in[16];
    const float* ln_out_g = (const float*)d_in[17];
    const float* ln_out_b = (const float*)d_in[18];
    unsigned short* ws = (unsigned short*)d_ws;
    float* out = (float*)d_out;

    convert_weights<<<(TOTAL_W + 255) / 256, 256, 0, stream>>>(
        Wp, Wg1, We1, We2, We3, Wg2, Wg3, ws);
    moe_main<<<B_ROWS / M_TILE, 256, 0, stream>>>(
        x, ln_in_g, ln_in_b, bp, bg1, bg2, bg3,
        be1, be2, be3, ln_out_g, ln_out_b, ws, out);
}